// Round 11
// baseline (293.630 us; speedup 1.0000x reference)
//
#include <hip/hip_runtime.h>
#include <hip/hip_bf16.h>

#define TSEQ 2048
#define TBZ  32
#define TDIM 1024
#define NLS  8

typedef __attribute__((ext_vector_type(8))) short bf16x8;
typedef __attribute__((ext_vector_type(4))) float f32x4;

__device__ inline unsigned int pk2(float lo, float hi) {
    __hip_bfloat162 h = __float22bfloat162_rn(make_float2(lo, hi)); // v_cvt_pk_bf16_f32
    return *reinterpret_cast<const unsigned int*>(&h);
}

__device__ inline void gload_lds16(const void* g, void* l) {
    __builtin_amdgcn_global_load_lds(
        (const __attribute__((address_space(1))) unsigned int*)g,
        (__attribute__((address_space(3))) unsigned int*)l,
        16, 0, 0);
}

// ---------- pass 1: merged conversion, one dispatch, block-uniform roles ----
__global__ __launch_bounds__(256) void conv_all(
    const float* __restrict__ x, const int* __restrict__ lang_ids,
    const float* __restrict__ W,
    unsigned short* __restrict__ xb, unsigned short* __restrict__ wb,
    float* __restrict__ out)
{
    const int bid = blockIdx.x;
    if (bid < 256) {                               // W part: 1M chunks of 8
        const int total = NLS * TDIM * TDIM / 8;
        for (int i = bid * 256 + threadIdx.x; i < total; i += 256 * 256) {
            const float* src = W + (long)i * 8;
            f32x4 v0 = *(const f32x4*)(src);
            f32x4 v1 = *(const f32x4*)(src + 4);
            uint4 o;
            o.x = pk2(v0.x, v0.y); o.y = pk2(v0.z, v0.w);
            o.z = pk2(v1.x, v1.y); o.w = pk2(v1.z, v1.w);
            *(uint4*)(wb + (long)i * 8) = o;
        }
        return;
    }
    // x part: 2048 blocks = 32 b x 64 s-chunks of 32 rows, block-uniform b
    const int xb_id = bid - 256;
    const int b     = xb_id >> 6;
    const int s0c   = (xb_id & 63) * 32;
    const int gid   = 8 - lang_ids[b];
    const bool active = (gid >= 1) && (gid <= 8);

    for (int i = threadIdx.x; i < 32 * 128; i += 256) {
        const int ls = i >> 7;
        const int d8 = i & 127;
        const int s  = s0c + ls;
        const float* src = x + ((long)s * TBZ + b) * TDIM + d8 * 8;
        f32x4 v0 = *(const f32x4*)(src);
        f32x4 v1 = *(const f32x4*)(src + 4);
        if (active) {
            uint4 o;
            o.x = pk2(v0.x, v0.y); o.y = pk2(v0.z, v0.w);
            o.z = pk2(v1.x, v1.y); o.w = pk2(v1.z, v1.w);
            *(uint4*)(xb + ((long)b * TSEQ + s) * TDIM + d8 * 8) = o;
        } else {
            float* dst = out + ((long)s * TBZ + b) * TDIM + d8 * 8;
            *(f32x4*)(dst)     = v0;
            *(f32x4*)(dst + 4) = v1;
        }
    }
}

// ---------- pass 2: persistent 256x256 8-phase bf16 GEMM, 4 m-tiles/block ----
// CHANGE vs r10: register-fragment ds_reads PIPELINED ONE PHASE AHEAD of
// their consuming MM (the m196 "fine ds_read || MFMA interleave" lever our
// port dropped). Phase-level audit: read drains were [1130,376,753,0]cy
// phase-locked + MFMA 621cy/phase + barriers = 11.1k cy/iter == measured
// 11.85k (fully serial). Moving each read a phase early lets the LDS unit
// drain it under the PREVIOUS MM's execution -> iter -> ~max() not sum.
//
// Read placement (af array shared: mh0 values live through P2's MM, so mh1
// reads can't start before P2-tail; same for tile b at P6):
//   P8-tail (after VMC6): RD_A(0,0)+RD_B(0,0)  -> consumed P1,P2,P3
//   P1:                   RD_B(0,1)            -> consumed P2,P4
//   P2-tail (after MM):   RD_A(0,1)            -> consumed P3,P4
//   P4-tail (after VMC6): RD_A(1,0)+RD_B(1,0)  -> consumed P5,P6,P7
//   P5:                   RD_B(1,1)            -> consumed P6,P8
//   P6-tail (after MM):   RD_A(1,1)            -> consumed P7,P8
// Staged-data-landed ledger (every read's source stage is inside the drained
// prefix of the last VMC(6); instr-counted): P8 VMC6 drains stages P2..P5 of
// this iter -> slot0 mh0(P2)/nh0(P3) landed for P8-tail reads; P4 VMC6
// drains P6',P7',P8',P1 -> slot1 mh0(P6')/nh0(P7')/mh1(P1) + nh1(P8')
// landed for P4/P5/P6 reads; prologue VMC6 drains its first 4 stage-pairs
// -> slot0 fully landed for prologue-tail + first-iter P1/P2 reads.
// Overwrite-before-read: each moved read drains (compiler lgkm wait at its
// consumer MM, <=2 phases later) before the stage that re-targets its LDS
// region lands (>=3 phases later). Registers: arrays reused, no growth --
// 128 VGPR + 128 AGPR acc = 256/wave is exactly the 2-wave/SIMD budget.

#define BAR __builtin_amdgcn_s_barrier()
#define SB0 __builtin_amdgcn_sched_barrier(0)
#define VMC(n) asm volatile("s_waitcnt vmcnt(" #n ")" ::: "memory")
#define KAo(kv) (((kv) & 1023) + (((kv) >> 10) << 18))
#define KBo(kv) ((kv) & 1023)

__global__ __launch_bounds__(512, 2) void mapper_gemm8p(
    const unsigned short* __restrict__ xb,      // [b][s][d] bf16
    const int* __restrict__ lang_ids,
    const unsigned short* __restrict__ wb,      // [e][out][in] bf16
    const float* __restrict__ bias,
    float* __restrict__ out)
{
    // XCD-chunked bijective swizzle: 256 = 8 * 32; nt fastest.
    const int p  = blockIdx.x;
    const int l  = (p & 7) * 32 + (p >> 3);
    const int b  = l >> 3;
    const int strip = (l >> 2) & 1;             // 4 m-tiles per strip
    const int nt = l & 3;
    const int s0 = strip * 1024;
    const int e0 = nt * 256;
    const int tid = threadIdx.x;

    const int gid = 8 - lang_ids[b];
    if (!(gid >= 1 && gid <= 8)) return;        // conv_all wrote passthrough
    const int eb = gid - 1;

    __shared__ uint4 ldsbuf[131072 / 16];
    char* ldsc = (char*)ldsbuf;

    const int lane = tid & 63;
    const int wave = tid >> 6;
    const int wr   = wave >> 2;
    const int wc   = wave & 3;
    const int fr   = lane & 15;
    const int fq   = lane >> 4;
    const int fr7  = fr & 7;

    const unsigned short* __restrict__ Aab = xb + (long)b  * TSEQ * TDIM + (long)s0 * TDIM;
    const unsigned short* __restrict__ Bbb = wb + (long)eb * TDIM * TDIM + (long)e0 * TDIM;

    const int L    = lane;
    const int lch8 = ((L & 7) ^ (L >> 3)) * 8;   // pre-inverse-swizzled global chunk
    const int ldA0 = wave * 2048 + L * 16;
    const unsigned short* aG[2][2];
    const unsigned short* bG[2][2];
    #pragma unroll
    for (int j = 0; j < 2; ++j) {
        const int rr = wave * 16 + j * 8 + (L >> 3);
        #pragma unroll
        for (int mh = 0; mh < 2; ++mh)
            aG[j][mh] = Aab + ((rr >> 6) * 128 + mh * 64 + (rr & 63)) * TDIM + lch8;
        #pragma unroll
        for (int nh = 0; nh < 2; ++nh)
            bG[j][nh] = Bbb + ((rr >> 5) * 64 + nh * 32 + (rr & 31)) * TDIM + lch8;
    }

#define STAGE_A(slot, mh, kofs) do { \
    gload_lds16(aG[0][mh] + (kofs), ldsc + (slot)*32768 + (mh)*16384 + ldA0); \
    gload_lds16(aG[1][mh] + (kofs), ldsc + (slot)*32768 + (mh)*16384 + ldA0 + 1024); \
} while (0)
#define STAGE_B(slot, nh, kofs) do { \
    gload_lds16(bG[0][nh] + (kofs), ldsc + 65536 + (slot)*32768 + (nh)*16384 + ldA0); \
    gload_lds16(bG[1][nh] + (kofs), ldsc + 65536 + (slot)*32768 + (nh)*16384 + ldA0 + 1024); \
} while (0)
#define RD_A(slot, mh) do { \
    _Pragma("unroll") for (int ml = 0; ml < 4; ++ml) { \
        const int rr = wr * 64 + ml * 16 + fr; \
        _Pragma("unroll") for (int kk = 0; kk < 2; ++kk) \
            af[ml][kk] = *(const bf16x8*)(ldsc + (slot)*32768 + (mh)*16384 + rr*128 + (((kk*4+fq) ^ fr7) << 4)); \
    } } while (0)
#define RD_B(slot, nh, br) do { \
    _Pragma("unroll") for (int nl = 0; nl < 2; ++nl) { \
        const int rr = wc * 32 + nl * 16 + fr; \
        _Pragma("unroll") for (int kk = 0; kk < 2; ++kk) \
            br[nl][kk] = *(const bf16x8*)(ldsc + 65536 + (slot)*32768 + (nh)*16384 + rr*128 + (((kk*4+fq) ^ fr7) << 4)); \
    } } while (0)
// Swapped operands (C^T): col=lane&15 -> s_local, row=(lane>>4)*4+j -> e_local.
#define MM(mh, nh, br) do { \
    __builtin_amdgcn_s_setprio(1); \
    _Pragma("unroll") for (int ml = 0; ml < 4; ++ml) \
    _Pragma("unroll") for (int nl = 0; nl < 2; ++nl) \
    _Pragma("unroll") for (int kk = 0; kk < 2; ++kk) \
        acc[(mh)*4+ml][(nh)*2+nl] = __builtin_amdgcn_mfma_f32_16x16x32_bf16( \
            br[nl][kk], af[ml][kk], acc[(mh)*4+ml][(nh)*2+nl], 0, 0, 0); \
    __builtin_amdgcn_s_setprio(0); \
} while (0)

    f32x4 acc[8][4];
    #pragma unroll
    for (int m = 0; m < 8; ++m)
        #pragma unroll
        for (int n = 0; n < 4; ++n)
            acc[m][n] = (f32x4){0.f, 0.f, 0.f, 0.f};

    bf16x8 af[4][2], bf0[2][2], bf1[2][2];

    // prologue: tile0 all 4 halves + tile1 {Amh0,Bnh0,Bnh1}
    STAGE_A(0, 0, 0);  STAGE_B(0, 0, 0);  STAGE_B(0, 1, 0);  STAGE_A(0, 1, 0);
    STAGE_A(1, 0, 64); STAGE_B(1, 0, 64); STAGE_B(1, 1, 64);
    VMC(6); BAR; SB0;
    // prologue-tail reads (play the role of "P8-tail" for the first iter):
    RD_A(0, 0); RD_B(0, 0, bf0); SB0;

    const int cs  = lane & 15;          // s_local
    const int eqb = (lane >> 4) << 2;   // e_local base (4 consecutive)

    #pragma unroll 1
    for (int mtl = 0; mtl < 4; ++mtl) {
        #pragma unroll 1
        for (int it = 0; it < 8; ++it) {
            const int kva = mtl * 1024 + it * 128;
            const int kb = kva + 64;
            const int kn = kva + 128;   // wraps into next m-tile after it=7
            const int km = kva + 192;
            // P1: MM(0,0)a [ops from P8-tail]; read bf1 for P2/P4
            STAGE_A(1, 1, KAo(kb)); RD_B(0, 1, bf1);
            BAR; SB0; MM(0, 0, bf0); BAR; SB0;
            // P2: MM(0,1)a [af-mh0 + bf1]; then overwrite af with mh1 for P3/P4
            STAGE_A(0, 0, KAo(kn));
            BAR; SB0; MM(0, 1, bf1); SB0; RD_A(0, 1); BAR; SB0;
            // P3: MM(1,0)a [af-mh1 + bf0]
            STAGE_B(0, 0, KBo(kn));
            BAR; SB0; MM(1, 0, bf0); BAR; SB0;
            // P4: MM(1,1)a [all old]; VMC6; read tile-b mh0/nh0 for P5..P7
            STAGE_B(0, 1, KBo(kn));
            BAR; SB0; MM(1, 1, bf1); VMC(6); SB0; RD_A(1, 0); RD_B(1, 0, bf0);
            BAR; SB0;
            // P5: MM(0,0)b; read bf1 for P6/P8
            STAGE_A(0, 1, KAo(kn)); RD_B(1, 1, bf1);
            BAR; SB0; MM(0, 0, bf0); BAR; SB0;
            // P6: MM(0,1)b; then af <- mh1 (tile b) for P7/P8
            STAGE_A(1, 0, KAo(km));
            BAR; SB0; MM(0, 1, bf1); SB0; RD_A(1, 1); BAR; SB0;
            // P7: MM(1,0)b
            STAGE_B(1, 0, KBo(km));
            BAR; SB0; MM(1, 0, bf0); BAR; SB0;
            // P8: MM(1,1)b; VMC6; read next-tile mh0/nh0 for next P1..P3
            STAGE_B(1, 1, KBo(km));
            BAR; SB0; MM(1, 1, bf1); VMC(6); SB0; RD_A(0, 0); RD_B(0, 0, bf0);
            BAR; SB0;
        }

        // epilogue: 32 dwordx4 stores; drain overlaps the bridge prefetch.
        // af/bf regs hold next-tile fragments (read at P8-tail) -- untouched.
        const int sb = s0 + mtl * 256 + wr * 128;
        #pragma unroll
        for (int n = 0; n < 4; ++n) {
            const int e = e0 + wc * 64 + n * 16 + eqb;
            const f32x4 bv4 = *(const f32x4*)&bias[eb * TDIM + e];
            #pragma unroll
            for (int m = 0; m < 8; ++m) {
                const int s = sb + m * 16 + cs;
                *(f32x4*)&out[(long)s * (TBZ * TDIM) + b * TDIM + e] = acc[m][n] + bv4;
            }
        }
        #pragma unroll
        for (int m = 0; m < 8; ++m)
            #pragma unroll
            for (int n = 0; n < 4; ++n)
                acc[m][n] = (f32x4){0.f, 0.f, 0.f, 0.f};
    }
#undef STAGE_A
#undef STAGE_B
#undef RD_A
#undef RD_B
#undef MM
}

// ---------- fallback: round-1 fused kernel ----------
__device__ inline unsigned short f2bf(float f) {
    union { float f; unsigned int u; } v; v.f = f;
    unsigned int r = v.u + 0x7fffu + ((v.u >> 16) & 1u);
    return (unsigned short)(r >> 16);
}
constexpr int FLDS = 40;

__global__ __launch_bounds__(256) void mapper_fused(
    const float* __restrict__ x, const int* __restrict__ lang_ids,
    const float* __restrict__ W, const float* __restrict__ bias,
    float* __restrict__ out)
{
    const int bid = blockIdx.x;
    const int b   = bid >> 7;
    const int t   = bid & 127;
    const int mt  = t >> 3;
    const int nt  = t & 7;
    const int s0  = mt * 128;
    const int e0  = nt * 128;
    const int tid = threadIdx.x;

    const int gid = 8 - lang_ids[b];
    const bool active = (gid >= 1) && (gid <= 8);
    int eb = gid - 1; eb = eb < 0 ? 0 : (eb > 7 ? 7 : eb);

    if (!active) {
        const f32x4* xs = (const f32x4*)x;
        f32x4*       os = (f32x4*)out;
        const int rs4 = TBZ * TDIM / 4;
        for (int i = tid; i < 128 * 128 / 4; i += 256) {
            int r = i >> 5, c = i & 31;
            long idx = (long)(s0 + r) * rs4 + b * (TDIM / 4) + (e0 >> 2) + c;
            os[idx] = xs[idx];
        }
        return;
    }

    __shared__ unsigned short As[128 * FLDS];
    __shared__ unsigned short Bs[128 * FLDS];
    const float* __restrict__ Wb = W + (long)eb * TDIM * TDIM;

    const int lane = tid & 63;
    const int wave = tid >> 6;
    const int wrr  = wave >> 1;
    const int wcc  = wave & 1;

    f32x4 acc[4][4];
    #pragma unroll
    for (int m = 0; m < 4; ++m)
        #pragma unroll
        for (int n = 0; n < 4; ++n)
            acc[m][n] = (f32x4){0.f, 0.f, 0.f, 0.f};

    const int rg = tid >> 3;
    const int cg = tid & 7;
    const int fr = lane & 15;
    const int fo = (lane >> 4) * 8;

    for (int k0 = 0; k0 < TDIM; k0 += 32) {
        __syncthreads();
        #pragma unroll
        for (int pp = 0; pp < 4; ++pp) {
            const int r = rg + pp * 32;
            f32x4 av = *(const f32x4*)(x  + (long)(s0 + r) * (TBZ * TDIM) + b * TDIM + k0 + cg * 4);
            f32x4 bv = *(const f32x4*)(Wb + (long)(e0 + r) * TDIM + k0 + cg * 4);
            unsigned int alo = (unsigned)f2bf(av.x) | ((unsigned)f2bf(av.y) << 16);
            unsigned int ahi = (unsigned)f2bf(av.z) | ((unsigned)f2bf(av.w) << 16);
            unsigned int blo = (unsigned)f2bf(bv.x) | ((unsigned)f2bf(bv.y) << 16);
            unsigned int bhi = (unsigned)f2bf(bv.z) | ((unsigned)f2bf(bv.w) << 16);
            *(uint2*)&As[r * FLDS + cg * 4] = make_uint2(alo, ahi);
            *(uint2*)&Bs[r * FLDS + cg * 4] = make_uint2(blo, bhi);
        }
        __syncthreads();

        bf16x8 af2[4], bfm[4];
        #pragma unroll
        for (int m = 0; m < 4; ++m)
            af2[m] = *(const bf16x8*)&As[(wrr * 64 + m * 16 + fr) * FLDS + fo];
        #pragma unroll
        for (int n = 0; n < 4; ++n)
            bfm[n] = *(const bf16x8*)&Bs[(wcc * 64 + n * 16 + fr) * FLDS + fo];
        #pragma unroll
        for (int m = 0; m < 4; ++m)
            #pragma unroll
            for (int n = 0; n < 4; ++n)
                acc[m][n] = __builtin_amdgcn_mfma_f32_16x16x32_bf16(af2[m], bfm[n], acc[m][n], 0, 0, 0);
    }

    const int cr = lane >> 4;
    const int cc2 = lane & 15;
    #pragma unroll
    for (int n = 0; n < 4; ++n) {
        const int e  = e0 + wcc * 64 + n * 16 + cc2;
        const float bv = bias[eb * TDIM + e];
        #pragma unroll
        for (int m = 0; m < 4; ++m) {
            #pragma unroll
            for (int j = 0; j < 4; ++j) {
                const int s = s0 + wrr * 64 + m * 16 + cr * 4 + j;
                out[(long)s * (TBZ * TDIM) + b * TDIM + e] = acc[m][n][j] + bv;
            }
        }
    }
}

extern "C" void kernel_launch(void* const* d_in, const int* in_sizes, int n_in,
                              void* d_out, int out_size, void* d_ws, size_t ws_size,
                              hipStream_t stream) {
    const float* x        = (const float*)d_in[0];
    const int*   lang_ids = (const int*)d_in[1];
    const float* W        = (const float*)d_in[2];
    const float* bias     = (const float*)d_in[3];
    float*       out      = (float*)d_out;

    const size_t xbytes = (size_t)TSEQ * TBZ * TDIM * 2;   // 128 MiB
    const size_t wbytes = (size_t)NLS * TDIM * TDIM * 2;   // 16 MiB

    if (ws_size >= xbytes + wbytes) {
        unsigned short* xbp = (unsigned short*)d_ws;
        unsigned short* wbp = (unsigned short*)((char*)d_ws + xbytes);
        conv_all<<<2304, 256, 0, stream>>>(x, lang_ids, W, xbp, wbp, out);
        mapper_gemm8p<<<256, 512, 0, stream>>>(xbp, lang_ids, wbp, bias, out);
    } else {
        mapper_fused<<<TBZ * 16 * 8, 256, 0, stream>>>(x, lang_ids, W, bias, out);
    }
}

// Round 12
// 272.112 us; speedup vs baseline: 1.0791x; 1.0791x over previous
//
#include <hip/hip_runtime.h>
#include <hip/hip_bf16.h>

#define TSEQ 2048
#define TBZ  32
#define TDIM 1024
#define NLS  8

typedef __attribute__((ext_vector_type(8))) short bf16x8;
typedef __attribute__((ext_vector_type(4))) float f32x4;

__device__ inline unsigned int pk2(float lo, float hi) {
    __hip_bfloat162 h = __float22bfloat162_rn(make_float2(lo, hi)); // v_cvt_pk_bf16_f32
    return *reinterpret_cast<const unsigned int*>(&h);
}

__device__ inline void gload_lds16(const void* g, void* l) {
    __builtin_amdgcn_global_load_lds(
        (const __attribute__((address_space(1))) unsigned int*)g,
        (__attribute__((address_space(3))) unsigned int*)l,
        16, 0, 0);
}

// ---------- pass 1: merged conversion, one dispatch, block-uniform roles ----
__global__ __launch_bounds__(256) void conv_all(
    const float* __restrict__ x, const int* __restrict__ lang_ids,
    const float* __restrict__ W,
    unsigned short* __restrict__ xb, unsigned short* __restrict__ wb,
    float* __restrict__ out)
{
    const int bid = blockIdx.x;
    if (bid < 256) {                               // W part: 1M chunks of 8
        const int total = NLS * TDIM * TDIM / 8;
        for (int i = bid * 256 + threadIdx.x; i < total; i += 256 * 256) {
            const float* src = W + (long)i * 8;
            f32x4 v0 = *(const f32x4*)(src);
            f32x4 v1 = *(const f32x4*)(src + 4);
            uint4 o;
            o.x = pk2(v0.x, v0.y); o.y = pk2(v0.z, v0.w);
            o.z = pk2(v1.x, v1.y); o.w = pk2(v1.z, v1.w);
            *(uint4*)(wb + (long)i * 8) = o;
        }
        return;
    }
    // x part: 2048 blocks = 32 b x 64 s-chunks of 32 rows, block-uniform b
    const int xb_id = bid - 256;
    const int b     = xb_id >> 6;
    const int s0c   = (xb_id & 63) * 32;
    const int gid   = 8 - lang_ids[b];
    const bool active = (gid >= 1) && (gid <= 8);

    for (int i = threadIdx.x; i < 32 * 128; i += 256) {
        const int ls = i >> 7;
        const int d8 = i & 127;
        const int s  = s0c + ls;
        const float* src = x + ((long)s * TBZ + b) * TDIM + d8 * 8;
        f32x4 v0 = *(const f32x4*)(src);
        f32x4 v1 = *(const f32x4*)(src + 4);
        if (active) {
            uint4 o;
            o.x = pk2(v0.x, v0.y); o.y = pk2(v0.z, v0.w);
            o.z = pk2(v1.x, v1.y); o.w = pk2(v1.z, v1.w);
            *(uint4*)(xb + ((long)b * TSEQ + s) * TDIM + d8 * 8) = o;
        } else {
            float* dst = out + ((long)s * TBZ + b) * TDIM + d8 * 8;
            *(f32x4*)(dst)     = v0;
            *(f32x4*)(dst + 4) = v1;
        }
    }
}

// ---------- pass 2: persistent 256x256 GEMM, 4-phase merged schedule ----------
// CHANGE vs r10 (single change): the 8 phases/iter merged pairwise into 4
// {reads, stages, BAR, 32-MFMA, BAR} phases. Barriers/iter 16->8; each
// doubled MFMA cluster gives the read drain a 2x window to stagger under.
// Re-derived ledger (STAGE = 2 loads):
//   stages: Q1: A(1,1,kb) | Q2: A(0,0,kn)+B(0,0,kn) | Q3: B(0,1,kn)+A(0,1,kn)
//           | Q4: A(1,0,km)+B(1,0,km)+B(1,1,km)
//   VMC(4) end-Q2: 6(prev)+2(Q1)+4(Q2)=12 -> drains prev-6 (slot1@kb for Q3)
//           + Q1's A(1,1,kb) (for Q4); leaves Q2's 4.
//   VMC(6) end-Q4: 4+4(Q3)+6(Q4)=14 -> drains Q2+Q3 (slot0@kn for next
//           Q1/Q2); leaves Q4's 6 = 3 half-tiles in flight (steady state).
//   Overwrite-safety: every stage issues >=1 barrier after its region's last
//   read drained (read drained by its consumer MM's lgkm wait, same phase).
//   Prologue identical to r10 (already matches the Q4-leftover shape).

#define BAR __builtin_amdgcn_s_barrier()
#define SB0 __builtin_amdgcn_sched_barrier(0)
#define VMC(n) asm volatile("s_waitcnt vmcnt(" #n ")" ::: "memory")
#define KAo(kv) (((kv) & 1023) + (((kv) >> 10) << 18))
#define KBo(kv) ((kv) & 1023)

__global__ __launch_bounds__(512, 2) void mapper_gemm8p(
    const unsigned short* __restrict__ xb,      // [b][s][d] bf16
    const int* __restrict__ lang_ids,
    const unsigned short* __restrict__ wb,      // [e][out][in] bf16
    const float* __restrict__ bias,
    float* __restrict__ out)
{
    // XCD-chunked bijective swizzle: 256 = 8 * 32; nt fastest.
    const int p  = blockIdx.x;
    const int l  = (p & 7) * 32 + (p >> 3);
    const int b  = l >> 3;
    const int strip = (l >> 2) & 1;             // 4 m-tiles per strip
    const int nt = l & 3;
    const int s0 = strip * 1024;
    const int e0 = nt * 256;
    const int tid = threadIdx.x;

    const int gid = 8 - lang_ids[b];
    if (!(gid >= 1 && gid <= 8)) return;        // conv_all wrote passthrough
    const int eb = gid - 1;

    __shared__ uint4 ldsbuf[131072 / 16];
    char* ldsc = (char*)ldsbuf;

    const int lane = tid & 63;
    const int wave = tid >> 6;
    const int wr   = wave >> 2;
    const int wc   = wave & 3;
    const int fr   = lane & 15;
    const int fq   = lane >> 4;
    const int fr7  = fr & 7;

    const unsigned short* __restrict__ Aab = xb + (long)b  * TSEQ * TDIM + (long)s0 * TDIM;
    const unsigned short* __restrict__ Bbb = wb + (long)eb * TDIM * TDIM + (long)e0 * TDIM;

    const int L    = lane;
    const int lch8 = ((L & 7) ^ (L >> 3)) * 8;   // pre-inverse-swizzled global chunk
    const int ldA0 = wave * 2048 + L * 16;
    const unsigned short* aG[2][2];
    const unsigned short* bG[2][2];
    #pragma unroll
    for (int j = 0; j < 2; ++j) {
        const int rr = wave * 16 + j * 8 + (L >> 3);
        #pragma unroll
        for (int mh = 0; mh < 2; ++mh)
            aG[j][mh] = Aab + ((rr >> 6) * 128 + mh * 64 + (rr & 63)) * TDIM + lch8;
        #pragma unroll
        for (int nh = 0; nh < 2; ++nh)
            bG[j][nh] = Bbb + ((rr >> 5) * 64 + nh * 32 + (rr & 31)) * TDIM + lch8;
    }

#define STAGE_A(slot, mh, kofs) do { \
    gload_lds16(aG[0][mh] + (kofs), ldsc + (slot)*32768 + (mh)*16384 + ldA0); \
    gload_lds16(aG[1][mh] + (kofs), ldsc + (slot)*32768 + (mh)*16384 + ldA0 + 1024); \
} while (0)
#define STAGE_B(slot, nh, kofs) do { \
    gload_lds16(bG[0][nh] + (kofs), ldsc + 65536 + (slot)*32768 + (nh)*16384 + ldA0); \
    gload_lds16(bG[1][nh] + (kofs), ldsc + 65536 + (slot)*32768 + (nh)*16384 + ldA0 + 1024); \
} while (0)
#define RD_A(slot, mh) do { \
    _Pragma("unroll") for (int ml = 0; ml < 4; ++ml) { \
        const int rr = wr * 64 + ml * 16 + fr; \
        _Pragma("unroll") for (int kk = 0; kk < 2; ++kk) \
            af[ml][kk] = *(const bf16x8*)(ldsc + (slot)*32768 + (mh)*16384 + rr*128 + (((kk*4+fq) ^ fr7) << 4)); \
    } } while (0)
#define RD_B(slot, nh, br) do { \
    _Pragma("unroll") for (int nl = 0; nl < 2; ++nl) { \
        const int rr = wc * 32 + nl * 16 + fr; \
        _Pragma("unroll") for (int kk = 0; kk < 2; ++kk) \
            br[nl][kk] = *(const bf16x8*)(ldsc + 65536 + (slot)*32768 + (nh)*16384 + rr*128 + (((kk*4+fq) ^ fr7) << 4)); \
    } } while (0)
// Swapped operands (C^T): col=lane&15 -> s_local, row=(lane>>4)*4+j -> e_local.
#define MM(mh, nh, br) do { \
    __builtin_amdgcn_s_setprio(1); \
    _Pragma("unroll") for (int ml = 0; ml < 4; ++ml) \
    _Pragma("unroll") for (int nl = 0; nl < 2; ++nl) \
    _Pragma("unroll") for (int kk = 0; kk < 2; ++kk) \
        acc[(mh)*4+ml][(nh)*2+nl] = __builtin_amdgcn_mfma_f32_16x16x32_bf16( \
            br[nl][kk], af[ml][kk], acc[(mh)*4+ml][(nh)*2+nl], 0, 0, 0); \
    __builtin_amdgcn_s_setprio(0); \
} while (0)

    f32x4 acc[8][4];
    #pragma unroll
    for (int m = 0; m < 8; ++m)
        #pragma unroll
        for (int n = 0; n < 4; ++n)
            acc[m][n] = (f32x4){0.f, 0.f, 0.f, 0.f};

    bf16x8 af[4][2], bf0[2][2], bf1[2][2];

    // prologue: tile0 all 4 halves + tile1 {Amh0,Bnh0,Bnh1}
    STAGE_A(0, 0, 0);  STAGE_B(0, 0, 0);  STAGE_B(0, 1, 0);  STAGE_A(0, 1, 0);
    STAGE_A(1, 0, 64); STAGE_B(1, 0, 64); STAGE_B(1, 1, 64);
    VMC(6); BAR; SB0;

    const int cs  = lane & 15;          // s_local
    const int eqb = (lane >> 4) << 2;   // e_local base (4 consecutive)

    #pragma unroll 1
    for (int mtl = 0; mtl < 4; ++mtl) {
        #pragma unroll 1
        for (int it = 0; it < 8; ++it) {
            const int kva = mtl * 1024 + it * 128;
            const int kb = kva + 64;
            const int kn = kva + 128;   // wraps into next m-tile after it=7
            const int km = kva + 192;
            // Q1: reads slot0 {A-mh0, B-nh0, B-nh1}; stage A(1,1)@kb
            RD_A(0, 0); RD_B(0, 0, bf0); RD_B(0, 1, bf1); STAGE_A(1, 1, KAo(kb));
            BAR; SB0; MM(0, 0, bf0); MM(0, 1, bf1); BAR; SB0;
            // Q2: read slot0 A-mh1; stage A(0,0)+B(0,0)@kn; VMC(4)
            RD_A(0, 1); STAGE_A(0, 0, KAo(kn)); STAGE_B(0, 0, KBo(kn));
            BAR; SB0; MM(1, 0, bf0); MM(1, 1, bf1); VMC(4); BAR; SB0;
            // Q3: reads slot1 {A-mh0, B-nh0, B-nh1}; stage B(0,1)+A(0,1)@kn
            RD_A(1, 0); RD_B(1, 0, bf0); RD_B(1, 1, bf1);
            STAGE_B(0, 1, KBo(kn)); STAGE_A(0, 1, KAo(kn));
            BAR; SB0; MM(0, 0, bf0); MM(0, 1, bf1); BAR; SB0;
            // Q4: read slot1 A-mh1; stage A(1,0)+B(1,0)+B(1,1)@km; VMC(6)
            RD_A(1, 1); STAGE_A(1, 0, KAo(km)); STAGE_B(1, 0, KBo(km)); STAGE_B(1, 1, KBo(km));
            BAR; SB0; MM(1, 0, bf0); MM(1, 1, bf1); VMC(6); BAR; SB0;
        }

        // epilogue: 32 dwordx4 stores; drain overlaps the bridge prefetch
        const int sb = s0 + mtl * 256 + wr * 128;
        #pragma unroll
        for (int n = 0; n < 4; ++n) {
            const int e = e0 + wc * 64 + n * 16 + eqb;
            const f32x4 bv4 = *(const f32x4*)&bias[eb * TDIM + e];
            #pragma unroll
            for (int m = 0; m < 8; ++m) {
                const int s = sb + m * 16 + cs;
                *(f32x4*)&out[(long)s * (TBZ * TDIM) + b * TDIM + e] = acc[m][n] + bv4;
            }
        }
        #pragma unroll
        for (int m = 0; m < 8; ++m)
            #pragma unroll
            for (int n = 0; n < 4; ++n)
                acc[m][n] = (f32x4){0.f, 0.f, 0.f, 0.f};
    }
#undef STAGE_A
#undef STAGE_B
#undef RD_A
#undef RD_B
#undef MM
}

// ---------- fallback: round-1 fused kernel ----------
__device__ inline unsigned short f2bf(float f) {
    union { float f; unsigned int u; } v; v.f = f;
    unsigned int r = v.u + 0x7fffu + ((v.u >> 16) & 1u);
    return (unsigned short)(r >> 16);
}
constexpr int FLDS = 40;

__global__ __launch_bounds__(256) void mapper_fused(
    const float* __restrict__ x, const int* __restrict__ lang_ids,
    const float* __restrict__ W, const float* __restrict__ bias,
    float* __restrict__ out)
{
    const int bid = blockIdx.x;
    const int b   = bid >> 7;
    const int t   = bid & 127;
    const int mt  = t >> 3;
    const int nt  = t & 7;
    const int s0  = mt * 128;
    const int e0  = nt * 128;
    const int tid = threadIdx.x;

    const int gid = 8 - lang_ids[b];
    const bool active = (gid >= 1) && (gid <= 8);
    int eb = gid - 1; eb = eb < 0 ? 0 : (eb > 7 ? 7 : eb);

    if (!active) {
        const f32x4* xs = (const f32x4*)x;
        f32x4*       os = (f32x4*)out;
        const int rs4 = TBZ * TDIM / 4;
        for (int i = tid; i < 128 * 128 / 4; i += 256) {
            int r = i >> 5, c = i & 31;
            long idx = (long)(s0 + r) * rs4 + b * (TDIM / 4) + (e0 >> 2) + c;
            os[idx] = xs[idx];
        }
        return;
    }

    __shared__ unsigned short As[128 * FLDS];
    __shared__ unsigned short Bs[128 * FLDS];
    const float* __restrict__ Wb = W + (long)eb * TDIM * TDIM;

    const int lane = tid & 63;
    const int wave = tid >> 6;
    const int wrr  = wave >> 1;
    const int wcc  = wave & 1;

    f32x4 acc[4][4];
    #pragma unroll
    for (int m = 0; m < 4; ++m)
        #pragma unroll
        for (int n = 0; n < 4; ++n)
            acc[m][n] = (f32x4){0.f, 0.f, 0.f, 0.f};

    const int rg = tid >> 3;
    const int cg = tid & 7;
    const int fr = lane & 15;
    const int fo = (lane >> 4) * 8;

    for (int k0 = 0; k0 < TDIM; k0 += 32) {
        __syncthreads();
        #pragma unroll
        for (int pp = 0; pp < 4; ++pp) {
            const int r = rg + pp * 32;
            f32x4 av = *(const f32x4*)(x  + (long)(s0 + r) * (TBZ * TDIM) + b * TDIM + k0 + cg * 4);
            f32x4 bv = *(const f32x4*)(Wb + (long)(e0 + r) * TDIM + k0 + cg * 4);
            unsigned int alo = (unsigned)f2bf(av.x) | ((unsigned)f2bf(av.y) << 16);
            unsigned int ahi = (unsigned)f2bf(av.z) | ((unsigned)f2bf(av.w) << 16);
            unsigned int blo = (unsigned)f2bf(bv.x) | ((unsigned)f2bf(bv.y) << 16);
            unsigned int bhi = (unsigned)f2bf(bv.z) | ((unsigned)f2bf(bv.w) << 16);
            *(uint2*)&As[r * FLDS + cg * 4] = make_uint2(alo, ahi);
            *(uint2*)&Bs[r * FLDS + cg * 4] = make_uint2(blo, bhi);
        }
        __syncthreads();

        bf16x8 af2[4], bfm[4];
        #pragma unroll
        for (int m = 0; m < 4; ++m)
            af2[m] = *(const bf16x8*)&As[(wrr * 64 + m * 16 + fr) * FLDS + fo];
        #pragma unroll
        for (int n = 0; n < 4; ++n)
            bfm[n] = *(const bf16x8*)&Bs[(wcc * 64 + n * 16 + fr) * FLDS + fo];
        #pragma unroll
        for (int m = 0; m < 4; ++m)
            #pragma unroll
            for (int n = 0; n < 4; ++n)
                acc[m][n] = __builtin_amdgcn_mfma_f32_16x16x32_bf16(af2[m], bfm[n], acc[m][n], 0, 0, 0);
    }

    const int cr = lane >> 4;
    const int cc2 = lane & 15;
    #pragma unroll
    for (int n = 0; n < 4; ++n) {
        const int e  = e0 + wcc * 64 + n * 16 + cc2;
        const float bv = bias[eb * TDIM + e];
        #pragma unroll
        for (int m = 0; m < 4; ++m) {
            #pragma unroll
            for (int j = 0; j < 4; ++j) {
                const int s = s0 + wrr * 64 + m * 16 + cr * 4 + j;
                out[(long)s * (TBZ * TDIM) + b * TDIM + e] = acc[m][n][j] + bv;
            }
        }
    }
}

extern "C" void kernel_launch(void* const* d_in, const int* in_sizes, int n_in,
                              void* d_out, int out_size, void* d_ws, size_t ws_size,
                              hipStream_t stream) {
    const float* x        = (const float*)d_in[0];
    const int*   lang_ids = (const int*)d_in[1];
    const float* W        = (const float*)d_in[2];
    const float* bias     = (const float*)d_in[3];
    float*       out      = (float*)d_out;

    const size_t xbytes = (size_t)TSEQ * TBZ * TDIM * 2;   // 128 MiB
    const size_t wbytes = (size_t)NLS * TDIM * TDIM * 2;   // 16 MiB

    if (ws_size >= xbytes + wbytes) {
        unsigned short* xbp = (unsigned short*)d_ws;
        unsigned short* wbp = (unsigned short*)((char*)d_ws + xbytes);
        conv_all<<<2304, 256, 0, stream>>>(x, lang_ids, W, xbp, wbp, out);
        mapper_gemm8p<<<256, 512, 0, stream>>>(xbp, lang_ids, wbp, bias, out);
    } else {
        mapper_fused<<<TBZ * 16 * 8, 256, 0, stream>>>(x, lang_ids, W, bias, out);
    }
}